// Round 1
// 1025.240 us; speedup vs baseline: 1.2192x; 1.2192x over previous
//
#include <hip/hip_runtime.h>

// Householder flow step, fused:
//   v_new = v @ W^T + b ; z_new = z - 2 v_new (v_new.z)/||v_new||^2
// B = 524288 rows, d = 128, all fp32.
//
// Layout: lane l owns output columns j = 2l, 2l+1 of its wave's rows.
// W staged transposed in LDS (Wt[k][j], stride 130 -> 8B aligned ds_read_b64,
// 2-way bank aliasing = free). v row values are wave-uniform, but are loaded
// through the VECTOR memory path (vmcnt) instead of s_load: SMEM + DS share
// lgkmcnt and complete out-of-order, forcing lgkmcnt(0) drains that exposed
// full scalar-load latency every k-chunk (VALUBusy was 19%). A VGPR-resident
// zero in the address forces global_load_dwordx4; uniform addresses coalesce
// to one request, so HBM traffic is unchanged.

#define ZD 128
#define LSTR 130          // 128 + 2 pad: even (b64 align) and breaks stride-128 write conflicts
#define BLOCK 1024        // 16 waves -> forces 4 waves/SIMD co-resident (VGPR <= 128)
#define ROWS_PER_WAVE 16
#define ROWS_PER_BLOCK 256
#define RGROUP 8

template<int R>
__device__ __forceinline__ void process_rows(
    const float* __restrict__ z, const float* __restrict__ v,
    float* __restrict__ out, const float* Wt,
    int row0, int lane, int vzero, float b0, float b1)
{
    float2 zr[R];
    float acc0[R], acc1[R];
    // vzero == 0 but lives in a VGPR the optimizer can't see through ->
    // the v loads go out as global_load_dwordx4 (vmcnt), not s_load (lgkmcnt).
    const float* vp = v + (size_t)row0 * ZD + vzero;
    #pragma unroll
    for (int r = 0; r < R; ++r) {
        zr[r] = *(const float2*)(z + (size_t)(row0 + r) * ZD + 2 * lane);
        acc0[r] = 0.f; acc1[r] = 0.f;
    }
    // 4-k chunks: 1 float4 VMEM load per row per chunk = 1 load : 16 FMAs.
    // unroll 4 -> 32 loads hoistable per body, covers L2/HBM latency.
    #pragma unroll 4
    for (int k0 = 0; k0 < ZD; k0 += 4) {
        float4 vv[R];
        #pragma unroll
        for (int r = 0; r < R; ++r)
            vv[r] = *(const float4*)(vp + r * ZD + k0);   // uniform addr -> 1 req/instr
        #pragma unroll
        for (int kk = 0; kk < 4; ++kk) {
            float2 wv = *(const float2*)(Wt + (k0 + kk) * LSTR + 2 * lane);  // ds_read_b64
            #pragma unroll
            for (int r = 0; r < R; ++r) {
                float vk = (kk == 0) ? vv[r].x :
                           (kk == 1) ? vv[r].y :
                           (kk == 2) ? vv[r].z : vv[r].w;   // kk is compile-time
                acc0[r] = fmaf(vk, wv.x, acc0[r]);
                acc1[r] = fmaf(vk, wv.y, acc1[r]);
            }
        }
    }
    #pragma unroll
    for (int r = 0; r < R; ++r) {
        float a0 = acc0[r] + b0;
        float a1 = acc1[r] + b1;
        float dot = a0 * zr[r].x + a1 * zr[r].y;
        float nrm = a0 * a0 + a1 * a1;
        #pragma unroll
        for (int off = 32; off; off >>= 1) {
            dot += __shfl_xor(dot, off);
            nrm += __shfl_xor(nrm, off);
        }
        float s = 2.0f * dot / nrm;
        float2 o;
        o.x = zr[r].x - s * a0;
        o.y = zr[r].y - s * a1;
        *(float2*)(out + (size_t)(row0 + r) * ZD + 2 * lane) = o;
    }
}

__global__ __launch_bounds__(BLOCK)
void hh_kernel(const float* __restrict__ z, const float* __restrict__ v,
               const float* __restrict__ W, const float* __restrict__ bias,
               float* __restrict__ out, int rows)
{
    __shared__ float Wt[ZD * LSTR];
    const int tid = threadIdx.x;
    // Stage W transposed: Wt[k*LSTR + j] = W[j*128 + k].
    // Global read coalesced; LDS write stride 130 dwords -> 2-way alias (free).
    #pragma unroll
    for (int i = tid; i < ZD * ZD; i += BLOCK) {
        int j = i >> 7, k = i & 127;
        Wt[k * LSTR + j] = W[i];
    }
    int vzero;
    asm volatile("v_mov_b32 %0, 0" : "=v"(vzero));   // opaque 0 in a VGPR
    __syncthreads();

    const int lane = tid & 63;
    const int wid  = __builtin_amdgcn_readfirstlane(tid >> 6);  // force uniform
    float2 bb = *(const float2*)(bias + 2 * lane);

    const int rowBase = blockIdx.x * ROWS_PER_BLOCK + wid * ROWS_PER_WAVE;
    #pragma unroll 1
    for (int t = 0; t < ROWS_PER_WAVE / RGROUP; ++t) {
        int row0 = rowBase + t * RGROUP;
        if (row0 >= rows) return;
        if (row0 + RGROUP <= rows) {
            process_rows<RGROUP>(z, v, out, Wt, row0, lane, vzero, bb.x, bb.y);
        } else {
            for (int r = 0; r < RGROUP && row0 + r < rows; ++r)
                process_rows<1>(z, v, out, Wt, row0 + r, lane, vzero, bb.x, bb.y);
        }
    }
}

extern "C" void kernel_launch(void* const* d_in, const int* in_sizes, int n_in,
                              void* d_out, int out_size, void* d_ws, size_t ws_size,
                              hipStream_t stream) {
    const float* z    = (const float*)d_in[0];
    const float* v    = (const float*)d_in[1];
    const float* W    = (const float*)d_in[2];
    const float* bias = (const float*)d_in[3];
    float* out = (float*)d_out;
    int rows = in_sizes[0] / ZD;
    int grid = (rows + ROWS_PER_BLOCK - 1) / ROWS_PER_BLOCK;
    hh_kernel<<<grid, BLOCK, 0, stream>>>(z, v, W, bias, out, rows);
}

// Round 2
// 610.234 us; speedup vs baseline: 2.0483x; 1.6801x over previous
//
#include <hip/hip_runtime.h>

// Householder flow step via bf16-split MFMA:
//   v_new = v @ W^T + b ; z_new = z - 2 v_new (v_new.z)/||v_new||^2
// B = 524288 rows, d = 128, fp32 in/out.
//
// The 128x128 GEMM runs on matrix cores: v = vh + vl, W = wh + wl (bf16
// truncation splits), all 4 cross products accumulated in fp32 -> products
// exact to ~2^-16 relative (error ~1e-4, well under the passing 0.0156
// absmax). MFMA cost is ~7 us device-wide; kernel becomes memory-bound
// (768 MB @ 6.3 TB/s = 122 us floor).
//
// Fragment-layout safety: C/D layout is the HW-verified col=lane&15,
// row=(lane>>4)*4+reg. For A/B, D = sum_k A[i,k]B[k,j] is invariant to any
// k-permutation applied consistently to BOTH operands (A and B share the
// same lane->k map on this shape), so we pick one k-map (kmap below) and
// use it for both the LDS-staged W fragments and the global v fragment
// loads -- correctness does not depend on the exact HW k-ordering.

#define ZD 128
#define BLOCK 512              // 8 waves
#define ROWS_PER_CHUNK 128     // 8 waves x 16-row M-strip each
#define CHUNKS_PER_BLOCK 2

typedef __bf16 bf16x8 __attribute__((ext_vector_type(8)));
typedef float f32x4 __attribute__((ext_vector_type(4)));
typedef unsigned int uint4v __attribute__((ext_vector_type(4)));

// k-slot map within one 32-k MFMA step: k = 4*g + (j&3) + 16*(j>>2),
// g = lane>>4, j = bf16 reg index 0..7. (Two contiguous float4s per lane.)

__global__ __launch_bounds__(BLOCK, 4)
void hh_mfma(const float* __restrict__ z, const float* __restrict__ v,
             const float* __restrict__ W, const float* __restrict__ bias,
             float* __restrict__ out, int rows)
{
    // B-fragments of W^T, hi/lo bf16 splits. [s][t][lane][j] ushorts.
    __shared__ __align__(16) unsigned short Bh[4 * 8 * 64 * 8];  // 32 KB
    __shared__ __align__(16) unsigned short Bl[4 * 8 * 64 * 8];  // 32 KB

    const int tid = threadIdx.x;
    // Stage + split W once per block. i = n*128 + k, element W[n][k];
    // B[k][n] = W[n][k] goes to tile t=n>>4, kstep s=k>>5, lane g*16+(n&15).
    for (int i = tid; i < ZD * ZD; i += BLOCK) {
        int n = i >> 7, k = i & 127;
        float w = W[i];
        unsigned b  = __float_as_uint(w);
        unsigned hb = b & 0xFFFF0000u;
        unsigned lb = __float_as_uint(w - __uint_as_float(hb));
        int s  = k >> 5, kk = k & 31;
        int g  = (kk >> 2) & 3;
        int j  = (kk & 3) + ((kk >> 4) & 1) * 4;   // inverse of kmap
        int t  = n >> 4;
        int l  = g * 16 + (n & 15);
        int idx = (((s * 8 + t) * 64) + l) * 8 + j;
        Bh[idx] = (unsigned short)(hb >> 16);
        Bl[idx] = (unsigned short)(lb >> 16);
    }
    __syncthreads();

    const int lane = tid & 63;
    const int wid  = tid >> 6;
    const int col0 = lane & 15;     // C col / A row / B col (within tile)
    const int g    = lane >> 4;

    float bt[8];
    #pragma unroll
    for (int t = 0; t < 8; ++t) bt[t] = bias[t * 16 + col0];

    #pragma unroll 1
    for (int c = 0; c < CHUNKS_PER_BLOCK; ++c) {
        const int row0 = (blockIdx.x * CHUNKS_PER_BLOCK + c) * ROWS_PER_CHUNK
                         + wid * 16;
        if (row0 >= rows) continue;

        f32x4 acc[8];
        #pragma unroll
        for (int t = 0; t < 8; ++t) acc[t] = (f32x4){0.f, 0.f, 0.f, 0.f};

        int ar = row0 + col0;                 // A row this lane supplies
        if (ar >= rows) ar = rows - 1;        // clamp: tail rows harmless
        const float* vrow = v + (size_t)ar * ZD + 4 * g;

        #pragma unroll
        for (int s = 0; s < 4; ++s) {
            // A fragment: k = s*32 + 4g + {0..3} and + 16 + {0..3}
            float4 va = *(const float4*)(vrow + s * 32);
            float4 vb = *(const float4*)(vrow + s * 32 + 16);
            float f[8] = {va.x, va.y, va.z, va.w, vb.x, vb.y, vb.z, vb.w};
            unsigned hb[8], lb[8];
            #pragma unroll
            for (int e = 0; e < 8; ++e) {
                unsigned bbits = __float_as_uint(f[e]);
                hb[e] = bbits & 0xFFFF0000u;
                lb[e] = __float_as_uint(f[e] - __uint_as_float(hb[e]));
            }
            uint4v ahw = { (hb[0] >> 16) | hb[1],
                           (hb[2] >> 16) | hb[3],
                           (hb[4] >> 16) | hb[5],
                           (hb[6] >> 16) | hb[7] };
            uint4v alw = { (lb[0] >> 16) | (lb[1] & 0xFFFF0000u),
                           (lb[2] >> 16) | (lb[3] & 0xFFFF0000u),
                           (lb[4] >> 16) | (lb[5] & 0xFFFF0000u),
                           (lb[6] >> 16) | (lb[7] & 0xFFFF0000u) };
            bf16x8 ah = __builtin_bit_cast(bf16x8, ahw);
            bf16x8 al = __builtin_bit_cast(bf16x8, alw);

            #pragma unroll
            for (int t = 0; t < 8; ++t) {
                const int bidx = (((s * 8 + t) * 64) + lane) * 8;
                bf16x8 bh = __builtin_bit_cast(bf16x8, *(const uint4v*)&Bh[bidx]);
                bf16x8 bl = __builtin_bit_cast(bf16x8, *(const uint4v*)&Bl[bidx]);
                acc[t] = __builtin_amdgcn_mfma_f32_16x16x32_bf16(ah, bh, acc[t], 0, 0, 0);
                acc[t] = __builtin_amdgcn_mfma_f32_16x16x32_bf16(al, bh, acc[t], 0, 0, 0);
                acc[t] = __builtin_amdgcn_mfma_f32_16x16x32_bf16(ah, bl, acc[t], 0, 0, 0);
                acc[t] = __builtin_amdgcn_mfma_f32_16x16x32_bf16(al, bl, acc[t], 0, 0, 0);
            }
        }

        // Epilogue. C layout: col = t*16+col0, row = row0 + 4g + q.
        #pragma unroll
        for (int t = 0; t < 8; ++t)
            #pragma unroll
            for (int q = 0; q < 4; ++q) acc[t][q] += bt[t];

        const int rb = row0 + g * 4;
        float zv[8][4];
        #pragma unroll
        for (int q = 0; q < 4; ++q) {
            int m = rb + q; if (m >= rows) m = rows - 1;
            const float* zp = z + (size_t)m * ZD + col0;
            #pragma unroll
            for (int t = 0; t < 8; ++t) zv[t][q] = zp[t * 16];
        }
        float pd[4], pn[4];
        #pragma unroll
        for (int q = 0; q < 4; ++q) {
            pd[q] = 0.f; pn[q] = 0.f;
            #pragma unroll
            for (int t = 0; t < 8; ++t) {
                pd[q] = fmaf(acc[t][q], zv[t][q], pd[q]);
                pn[q] = fmaf(acc[t][q], acc[t][q], pn[q]);
            }
        }
        #pragma unroll
        for (int off = 1; off <= 8; off <<= 1) {
            #pragma unroll
            for (int q = 0; q < 4; ++q) {
                pd[q] += __shfl_xor(pd[q], off);
                pn[q] += __shfl_xor(pn[q], off);
            }
        }
        #pragma unroll
        for (int q = 0; q < 4; ++q) {
            int m = rb + q;
            if (m < rows) {
                float sc = 2.0f * pd[q] / pn[q];
                float* op = out + (size_t)m * ZD + col0;
                #pragma unroll
                for (int t = 0; t < 8; ++t)
                    op[t * 16] = fmaf(-sc, acc[t][q], zv[t][q]);
            }
        }
    }
}

extern "C" void kernel_launch(void* const* d_in, const int* in_sizes, int n_in,
                              void* d_out, int out_size, void* d_ws, size_t ws_size,
                              hipStream_t stream) {
    const float* z    = (const float*)d_in[0];
    const float* v    = (const float*)d_in[1];
    const float* W    = (const float*)d_in[2];
    const float* bias = (const float*)d_in[3];
    float* out = (float*)d_out;
    int rows = in_sizes[0] / ZD;
    const int rpb = ROWS_PER_CHUNK * CHUNKS_PER_BLOCK;
    int grid = (rows + rpb - 1) / rpb;
    hh_mfma<<<grid, BLOCK, 0, stream>>>(z, v, W, bias, out, rows);
}